// Round 3
// baseline (258.380 us; speedup 1.0000x reference)
//
#include <hip/hip_runtime.h>
#include <math.h>

// Problem constants (fixed by reference file)
#define NB   2
#define LQ   16384
#define CDIM 256
#define MH   8          // heads
#define DH   32         // head dim
#define LIN  21760      // 128^2+64^2+32^2+16^2
#define NPIX (NB * LIN) // 43520 total pixels across batch

typedef __attribute__((ext_vector_type(8))) _Float16 f16x8;
typedef __attribute__((ext_vector_type(4))) _Float16 f16x4;
typedef __attribute__((ext_vector_type(4))) float    f32x4;

// async 16B global->LDS (wave-uniform LDS base + lane*16 — no padding allowed)
__device__ __forceinline__ void async16(const void* g, void* l) {
    __builtin_amdgcn_global_load_lds(
        (const __attribute__((address_space(1))) void*)g,
        (__attribute__((address_space(3))) void*)l,
        16, 0, 0);
}

// ---------------- merged weight transposes: W[k][n] f32 -> t[n][k] f16 ----------
__global__ __launch_bounds__(256) void tsplit_all_kernel(
    const float* __restrict__ Wv, const float* __restrict__ Wo,
    const float* __restrict__ Wf, const float* __restrict__ Wa,
    _Float16* __restrict__ Wvt, _Float16* __restrict__ Wot, _Float16* __restrict__ Wct)
{
    const int i = blockIdx.x * 256 + threadIdx.x;   // 896*256 exact
    const int r = i >> 8;
    const int kk = i & 255;
    if (r < 256) {
        Wvt[r * 256 + kk] = (_Float16)Wv[kk * 256 + r];
    } else if (r < 512) {
        const int n = r - 256;
        Wot[n * 256 + kk] = (_Float16)Wo[kk * 256 + n];
    } else if (r < 768) {
        const int n = r - 512;
        Wct[n * 256 + kk] = (_Float16)Wf[kk * 256 + n];
    } else {
        const int n = r - 768;
        Wct[(256 + n) * 256 + kk] = (_Float16)Wa[kk * 128 + n];
    }
}

// ---------------- f16 MFMA GEMM v2: dbuf prefetch + XOR-swizzled LDS + ----------
// ---------------- operand-swapped vectorized epilogue                 ----------
// C = A @ B + bias. A: MxK row-major (f32 converted in-kernel if A_F32, else f16).
// Bt: [N][K] f16. Tile 128x128x32, 256 threads.
// LDS swizzle (both-sides, rule #21): global_load_lds dest is linear; the SOURCE
//   k-chunk is XOR'd with row bits, reads apply the same XOR -> conflict-free
//   (2 lanes/bank) instead of 8-way on 64B/128B rows.
// Pipeline: stage(t+1) issued BEFORE computing tile t; ONE __syncthreads per step
//   (drains vmcnt incl. next-tile loads AFTER this tile's MFMAs -> latency hidden).
// Epilogue: mfma(bh, ah) gives thread 4 CONSECUTIVE COLS (col=quad*4+reg,
//   row=l16) -> float4 / f16x4 stores (16 wide stores vs 64 scalar).
// OUT_MODE: 0 = f32 flat, 1 = f16 flat, 2 = f16 head-major (m, pixel, 32ch).
template <int OUT_MODE, bool A_F32>
__global__ __launch_bounds__(256) void gemm_f16(
    const void* __restrict__ Araw, const _Float16* __restrict__ Bt,
    const float* __restrict__ bias0, const float* __restrict__ bias1,
    void* __restrict__ C0, void* __restrict__ C1,
    int M, int N, int K, int N0)
{
    __shared__ __align__(16) char AshRaw[2][A_F32 ? 128 * 32 * 4 : 128 * 32 * 2];
    __shared__ __align__(16) _Float16 Bsh[2][128 * 32];

    const int tid  = threadIdx.x;
    const int wave = tid >> 6, lane = tid & 63;
    const int quad = lane >> 4, l16 = lane & 15;
    const int bm = blockIdx.y * 128;
    const int bn = blockIdx.x * 128;
    const int wrow = wave * 32;

    f32x4 acc[2][8] = {};

    // f16 staging tasks (B always; A when !A_F32): row = s>>2, phys chunk = s&3,
    // source logical chunk = phys ^ ((row>>1)&3)
    const int sB0 = tid, sB1 = tid + 256;
    const int rB0 = sB0 >> 2, rB1 = sB1 >> 2;
    const int kB0 = ((sB0 & 3) ^ ((rB0 >> 1) & 3)) << 3;
    const int kB1 = ((sB1 & 3) ^ ((rB1 >> 1) & 3)) << 3;

    const int T = K >> 5;
    int cur = 0;

    auto stage = [&](int buf, int k0) {
        if (A_F32) {
            const float* A = (const float*)Araw;
            float* AshF = (float*)AshRaw[buf];
            #pragma unroll
            for (int j = 0; j < 4; ++j) {
                const int s = tid + 256 * j;
                const int row = s >> 3;
                const int kg = ((s & 7) ^ (row & 7)) << 2;   // f32 elems
                async16(A + (size_t)(bm + row) * K + k0 + kg, AshF + s * 4);
            }
        } else {
            const _Float16* A = (const _Float16*)Araw;
            _Float16* Ash = (_Float16*)AshRaw[buf];
            async16(A + (size_t)(bm + rB0) * K + k0 + kB0, Ash + sB0 * 8);
            async16(A + (size_t)(bm + rB1) * K + k0 + kB1, Ash + sB1 * 8);
        }
        async16(Bt + (size_t)(bn + rB0) * K + k0 + kB0, Bsh[buf] + sB0 * 8);
        async16(Bt + (size_t)(bn + rB1) * K + k0 + kB1, Bsh[buf] + sB1 * 8);
    };

    stage(0, 0);
    __syncthreads();

    for (int t = 0; t < T; ++t) {
        if (t + 1 < T) stage(cur ^ 1, (t + 1) << 5);

        f16x8 ah[2];
        #pragma unroll
        for (int r = 0; r < 2; ++r) {
            const int arow = wrow + r * 16 + l16;
            if (A_F32) {
                const float* AshF = (const float*)AshRaw[cur];
                const int c0 = (2 * quad)     ^ (arow & 7);
                const int c1 = (2 * quad + 1) ^ (arow & 7);
                const f32x4 a0 = *(const f32x4*)&AshF[arow * 32 + c0 * 4];
                const f32x4 a1 = *(const f32x4*)&AshF[arow * 32 + c1 * 4];
                f16x8 h;
                h[0] = (_Float16)a0[0]; h[1] = (_Float16)a0[1];
                h[2] = (_Float16)a0[2]; h[3] = (_Float16)a0[3];
                h[4] = (_Float16)a1[0]; h[5] = (_Float16)a1[1];
                h[6] = (_Float16)a1[2]; h[7] = (_Float16)a1[3];
                ah[r] = h;
            } else {
                const _Float16* Ash = (const _Float16*)AshRaw[cur];
                ah[r] = *(const f16x8*)&Ash[arow * 32 + ((quad ^ ((arow >> 1) & 3)) << 3)];
            }
        }
        #pragma unroll
        for (int half = 0; half < 2; ++half) {
            f16x8 bh[4];
            #pragma unroll
            for (int c = 0; c < 4; ++c) {
                const int brow = half * 64 + c * 16 + l16;
                bh[c] = *(const f16x8*)&Bsh[cur][brow * 32 + ((quad ^ ((brow >> 1) & 3)) << 3)];
            }
            // SWAPPED operands: D^T fragment -> thread holds 4 consecutive C-cols
            #pragma unroll
            for (int r = 0; r < 2; ++r)
                #pragma unroll
                for (int c = 0; c < 4; ++c)
                    acc[r][half * 4 + c] = __builtin_amdgcn_mfma_f32_16x16x32_f16(
                        bh[c], ah[r], acc[r][half * 4 + c], 0, 0, 0);
        }
        __syncthreads();   // drains lgkm + vmcnt(0) (next-tile loads) + barrier
        cur ^= 1;
    }

    // epilogue (swapped layout): C-row = bm+wrow+r*16+l16, C-col = bn+cidx*16+quad*4+i
    void* Cb; const float* bb; int ldc, coff;
    if (bn < N0) { Cb = C0; bb = bias0; ldc = N0;     coff = 0;  }
    else         { Cb = C1; bb = bias1; ldc = N - N0; coff = N0; }
    #pragma unroll
    for (int cidx = 0; cidx < 8; ++cidx) {
        const int col = bn + cidx * 16 + quad * 4 - coff;   // 4 consecutive cols
        const float4 bia = *(const float4*)&bb[col];
        #pragma unroll
        for (int r = 0; r < 2; ++r) {
            const int rr = bm + wrow + r * 16 + l16;
            float4 v;
            v.x = acc[r][cidx][0] + bia.x;
            v.y = acc[r][cidx][1] + bia.y;
            v.z = acc[r][cidx][2] + bia.z;
            v.w = acc[r][cidx][3] + bia.w;
            if (OUT_MODE == 0) {
                *(float4*)&((float*)Cb)[(size_t)rr * ldc + col] = v;
            } else if (OUT_MODE == 1) {
                f16x4 h;
                h[0] = (_Float16)v.x; h[1] = (_Float16)v.y;
                h[2] = (_Float16)v.z; h[3] = (_Float16)v.w;
                *(f16x4*)&((_Float16*)Cb)[(size_t)rr * ldc + col] = h;
            } else {
                // head-major: col>>5 constant over the 4 (col%4==0, within a head)
                f16x4 h;
                h[0] = (_Float16)v.x; h[1] = (_Float16)v.y;
                h[2] = (_Float16)v.z; h[3] = (_Float16)v.w;
                *(f16x4*)&((_Float16*)Cb)[((size_t)(col >> 5) * NPIX + rr) * 32 + (col & 31)] = h;
            }
        }
    }
}

// ---------------- sampling v9: byte-offset saddr gathers + vector f32 math -------
// Same structure as v8 (head-major f16 taps, fused 16-lane shuffle softmax).
// Changes: LDS stores BYTE offsets (saddr+voffset addressing, 1 VALU/corner addr);
// accumulation as f32x4 vector expressions (compiler emits v_pk_fma_f32, halving
// FMA issue); d4 scaling folded once. Targets the 63% VALUBusy.
__global__ __launch_bounds__(256) void sample_kernel_v9(
    const _Float16* __restrict__ value,  // (MH, NPIX, 32) f16 head-major
    const float* __restrict__ off,       // (N*LQ, 256)
    const float* __restrict__ attn,      // (N*LQ, 128) RAW logits
    _Float16* __restrict__ outv)
{
    __shared__ __align__(16) float lds_task[8][516];

    const int tid = threadIdx.x;
    const int qbase = blockIdx.x * 4;

    #pragma unroll
    for (int j = 0; j < 2; ++j) {
        const int t  = tid + 256 * j;
        const int q  = t >> 7;
        const int m  = (t >> 4) & 7;
        const int pt = t & 15;          // pt = l*4 + p
        const int l  = pt >> 2;
        const int p  = pt & 3;
        const int qi = qbase + q;
        const int lq = qi & (LQ - 1);
        const int n  = qi >> 14;

        const int Hl = 128 >> l;
        const int STARTS[4] = {0, 16384, 20480, 21504};

        const float2 oxy = *(const float2*)&off[(size_t)qi * 256 + m * 32 + pt * 2];

        // fused softmax over the 16 logits of this (q,m) group (16-lane bijection)
        const float logit = attn[(size_t)qi * 128 + m * 16 + p * 4 + l];
        float mx = logit;
        #pragma unroll
        for (int d = 1; d < 16; d <<= 1) mx = fmaxf(mx, __shfl_xor(mx, d, 16));
        const float e = __expf(logit - mx);
        float sm = e;
        #pragma unroll
        for (int d = 1; d < 16; d <<= 1) sm += __shfl_xor(sm, d, 16);
        const float w = e / sm;

        const float refx = ((lq & 127) + 0.5f) * (1.0f / 128.0f);
        const float refy = ((lq >> 7)  + 0.5f) * (1.0f / 128.0f);

        const float x = refx * (float)Hl + oxy.x - 0.5f;
        const float y = refy * (float)Hl + oxy.y - 0.5f;
        const float x0f = floorf(x), y0f = floorf(y);
        const int x0 = (int)x0f, y0 = (int)y0f;
        const int x1 = x0 + 1,  y1 = y0 + 1;
        const float fx = x - x0f, fy = y - y0f;
        const float gx = 1.f - fx, gy = 1.f - fy;

        const float vx0 = (x0 >= 0 && x0 < Hl) ? 1.f : 0.f;
        const float vx1 = (x1 >= 0 && x1 < Hl) ? 1.f : 0.f;
        const float vy0 = (y0 >= 0 && y0 < Hl) ? 1.f : 0.f;
        const float vy1 = (y1 >= 0 && y1 < Hl) ? 1.f : 0.f;

        const int x0c = min(max(x0, 0), Hl - 1);
        const int x1c = min(max(x1, 0), Hl - 1);
        const int y0c = min(max(y0, 0), Hl - 1);
        const int y1c = min(max(y1, 0), Hl - 1);

        // head-major BYTE offsets; pixel stride 64 B
        const int baseb = m * (NPIX * 64) + (n * LIN + STARTS[l]) * 64;
        const int i00 = baseb + (y0c * Hl + x0c) * 64;
        const int i01 = baseb + (y0c * Hl + x1c) * 64;
        const int i10 = baseb + (y1c * Hl + x0c) * 64;
        const int i11 = baseb + (y1c * Hl + x1c) * 64;

        float4 wv;
        wv.x = w * gy * gx * vy0 * vx0;
        wv.y = w * gy * fx * vy0 * vx1;
        wv.z = w * fy * gx * vy1 * vx0;
        wv.w = w * fy * fx * vy1 * vx1;

        float* dst = &lds_task[m][(q * 16 + pt) * 8];
        int4 iv = {i00, i01, i10, i11};
        *(int4*)dst = iv;                 // bytes, 16B aligned
        *(float4*)(dst + 4) = wv;
    }
    __syncthreads();

    // ---- Phase 2: gather f16 taps + vector weighted accumulate ----
    const int q  = tid >> 6;
    const int m  = (tid >> 3) & 7;
    const int d4 = tid & 7;
    const int qi = qbase + q;
    const unsigned dd = (unsigned)(d4 * 8);     // byte offset of this lane's 4 ch
    const char* vp = (const char*)value;

    f32x4 acc = {0.f, 0.f, 0.f, 0.f};
    #pragma unroll
    for (int pt = 0; pt < 16; ++pt) {
        const float* td = &lds_task[m][(q * 16 + pt) * 8];
        const int4  iv = *(const int4*)td;
        const float4 wv = *(const float4*)(td + 4);
        const f16x4 v00 = *(const f16x4*)(vp + ((unsigned)iv.x + dd));
        const f16x4 v01 = *(const f16x4*)(vp + ((unsigned)iv.y + dd));
        const f16x4 v10 = *(const f16x4*)(vp + ((unsigned)iv.z + dd));
        const f16x4 v11 = *(const f16x4*)(vp + ((unsigned)iv.w + dd));
        f32x4 f00 = {(float)v00[0], (float)v00[1], (float)v00[2], (float)v00[3]};
        f32x4 f01 = {(float)v01[0], (float)v01[1], (float)v01[2], (float)v01[3]};
        f32x4 f10 = {(float)v10[0], (float)v10[1], (float)v10[2], (float)v10[3]};
        f32x4 f11 = {(float)v11[0], (float)v11[1], (float)v11[2], (float)v11[3]};
        acc += wv.x * f00 + wv.y * f01 + wv.z * f10 + wv.w * f11;  // v_pk_fma_f32
    }

    f16x4 o;
    o[0] = (_Float16)acc[0]; o[1] = (_Float16)acc[1];
    o[2] = (_Float16)acc[2]; o[3] = (_Float16)acc[3];
    *(f16x4*)&outv[(size_t)qi * 256 + m * 32 + d4 * 4] = o;
}

// ---------------- launch ----------------
extern "C" void kernel_launch(void* const* d_in, const int* in_sizes, int n_in,
                              void* d_out, int out_size, void* d_ws, size_t ws_size,
                              hipStream_t stream)
{
    const float* query         = (const float*)d_in[0];
    const float* input_flatten = (const float*)d_in[2];
    const float* W_off  = (const float*)d_in[5];
    const float* b_off  = (const float*)d_in[6];
    const float* W_attn = (const float*)d_in[7];
    const float* b_attn = (const float*)d_in[8];
    const float* W_val  = (const float*)d_in[9];
    const float* b_val  = (const float*)d_in[10];
    const float* W_out  = (const float*)d_in[11];
    const float* b_out  = (const float*)d_in[12];
    float* out = (float*)d_out;

    char* w = (char*)d_ws;
    _Float16* Sf16 = (_Float16*)w;                     // 16.8 MB, sampler->outGEMM
    _Float16* value16 = (_Float16*)(w + 23068672);     // (8, 43520, 32) f16 (22.3 MB)
    float*    attnbuf = (float*)(w + 67633152);        // 32768x128 f32 raw logits
    _Float16* Wvt = (_Float16*)(w + 84410368);         // [256][256] f16
    _Float16* Wot = Wvt + 65536;                       // [256][256] f16
    _Float16* Wct = Wot + 65536;                       // [384][256] f16 (off|attn)
    float* offbuf = out;   // off staged in d_out, consumed before final GEMM

    dim3 blk(256);

    // weight transforms (one merged launch)
    tsplit_all_kernel<<<896, blk, 0, stream>>>(W_val, W_out, W_off, W_attn, Wvt, Wot, Wct);

    // 1) value(f16, head-major) = IF(f32) @ W_val + b_val (in-GEMM conversion)
    gemm_f16<2, true><<<dim3(2, 340), blk, 0, stream>>>(
        input_flatten, Wvt, b_val, b_val, value16, value16, 43520, 256, 256, 256);

    // 2) fused off|attn GEMM on query f32 (routed epilogue, f32 out; attn = raw logits)
    gemm_f16<0, true><<<dim3(3, 256), blk, 0, stream>>>(
        query, Wct, b_off, b_attn, offbuf, attnbuf, 32768, 384, 256, 256);

    // 3) sampling: fused softmax + f16 head-major taps -> f16 sampled
    sample_kernel_v9<<<8192, blk, 0, stream>>>(value16, offbuf, attnbuf, Sf16);

    // 4) out = sampled @ W_out + b_out (f16 MFMA, f32 out)
    gemm_f16<0, false><<<dim3(2, 256), blk, 0, stream>>>(
        Sf16, Wot, b_out, b_out, out, out, 32768, 256, 256, 256);
}

// Round 4
// 237.267 us; speedup vs baseline: 1.0890x; 1.0890x over previous
//
#include <hip/hip_runtime.h>
#include <math.h>

// Problem constants (fixed by reference file)
#define NB   2
#define LQ   16384
#define CDIM 256
#define MH   8          // heads
#define DH   32         // head dim
#define LIN  21760      // 128^2+64^2+32^2+16^2
#define NPIX (NB * LIN) // 43520 total pixels across batch

typedef __attribute__((ext_vector_type(8))) _Float16 f16x8;
typedef __attribute__((ext_vector_type(4))) _Float16 f16x4;
typedef __attribute__((ext_vector_type(4))) float    f32x4;

// async 16B global->LDS (wave-uniform LDS base + lane*16 — no padding allowed)
__device__ __forceinline__ void async16(const void* g, void* l) {
    __builtin_amdgcn_global_load_lds(
        (const __attribute__((address_space(1))) void*)g,
        (__attribute__((address_space(3))) void*)l,
        16, 0, 0);
}

// ---------------- merged weight transposes: W[k][n] f32 -> t[n][k] f16 ----------
__global__ __launch_bounds__(256) void tsplit_all_kernel(
    const float* __restrict__ Wv, const float* __restrict__ Wo,
    const float* __restrict__ Wf, const float* __restrict__ Wa,
    _Float16* __restrict__ Wvt, _Float16* __restrict__ Wot, _Float16* __restrict__ Wct)
{
    const int i = blockIdx.x * 256 + threadIdx.x;   // 896*256 exact
    const int r = i >> 8;
    const int kk = i & 255;
    if (r < 256) {
        Wvt[r * 256 + kk] = (_Float16)Wv[kk * 256 + r];
    } else if (r < 512) {
        const int n = r - 256;
        Wot[n * 256 + kk] = (_Float16)Wo[kk * 256 + n];
    } else if (r < 768) {
        const int n = r - 512;
        Wct[n * 256 + kk] = (_Float16)Wf[kk * 256 + n];
    } else {
        const int n = r - 768;
        Wct[(256 + n) * 256 + kk] = (_Float16)Wa[kk * 128 + n];
    }
}

// ================= full-K=256 GEMM machinery =================
// Tile 128x128, K=256 fully LDS-resident (128 KB). One (f16-A) or three (f32-A)
// barriers TOTAL per block instead of 16 — kills the per-K-step vmcnt(0) drain
// that limited the thin-K GEMMs to ~95 TF.
// LDS swizzle (both-sides, rule #21): 16B-chunk phys = logical ^ (row & 7),
// applied to the GLOBAL SOURCE of global_load_lds (dest linear) and to reads
// -> 2 lanes/bank on all ds_read_b128 (free).
// MFMA operand-swapped (bh, ah) -> thread holds 4 consecutive C-cols -> wide stores.

// epilogue: C-row = bm+wave*32+r*16+l16, C-col = bn+cidx*16+quad*4+i
// OUT_MODE: 0 = f32 flat, 2 = f16 head-major (m, pixel, 32ch).
template <int OUT_MODE>
__device__ __forceinline__ void gemm_epilogue(
    f32x4 (&acc)[2][8], int bm, int bn, int wave, int quad, int l16,
    const float* bias0, const float* bias1, void* C0, void* C1, int N, int N0)
{
    void* Cb; const float* bb; int ldc, coff;
    if (bn < N0) { Cb = C0; bb = bias0; ldc = N0;     coff = 0;  }
    else         { Cb = C1; bb = bias1; ldc = N - N0; coff = N0; }
    #pragma unroll
    for (int cidx = 0; cidx < 8; ++cidx) {
        const int col = bn + cidx * 16 + quad * 4 - coff;   // 4 consecutive cols
        const float4 bia = *(const float4*)&bb[col];
        #pragma unroll
        for (int r = 0; r < 2; ++r) {
            const int rr = bm + wave * 32 + r * 16 + l16;
            float4 v;
            v.x = acc[r][cidx][0] + bia.x;
            v.y = acc[r][cidx][1] + bia.y;
            v.z = acc[r][cidx][2] + bia.z;
            v.w = acc[r][cidx][3] + bia.w;
            if (OUT_MODE == 0) {
                *(float4*)&((float*)Cb)[(size_t)rr * ldc + col] = v;
            } else {
                f16x4 h;
                h[0] = (_Float16)v.x; h[1] = (_Float16)v.y;
                h[2] = (_Float16)v.z; h[3] = (_Float16)v.w;
                *(f16x4*)&((_Float16*)Cb)[((size_t)(col >> 5) * NPIX + rr) * 32 + (col & 31)] = h;
            }
        }
    }
}

// stage B (f16 [128 rows][256 k], weights -> L2-resident): 16 async16/thread
__device__ __forceinline__ void stage_B(const _Float16* __restrict__ Bt, int bn,
                                        _Float16* Bsh, int tid)
{
    #pragma unroll
    for (int j = 0; j < 16; ++j) {
        const int s = tid + 256 * j;          // 16B slot; 32 slots/row
        const int row = s >> 5, phys = s & 31;
        const int cl = phys ^ (row & 7);      // inverse-swizzled source chunk
        async16(Bt + (size_t)(bn + row) * 256 + cl * 8, Bsh + s * 8);
    }
}

// B fragment read + 16 MFMAs for one K-step t (shared by both cores)
__device__ __forceinline__ void mfma_step(const _Float16* Bsh, const f16x8 (&ah)[2],
                                          int t, int quad, int l16, f32x4 (&acc)[2][8])
{
    #pragma unroll
    for (int half = 0; half < 2; ++half) {
        f16x8 bh[4];
        #pragma unroll
        for (int c = 0; c < 4; ++c) {
            const int brow = half * 64 + c * 16 + l16;
            const int pb = (t * 4 + quad) ^ (brow & 7);
            bh[c] = *(const f16x8*)&Bsh[brow * 256 + pb * 8];
        }
        #pragma unroll
        for (int r = 0; r < 2; ++r)
            #pragma unroll
            for (int c = 0; c < 4; ++c)
                acc[r][half * 4 + c] = __builtin_amdgcn_mfma_f32_16x16x32_f16(
                    bh[c], ah[r], acc[r][half * 4 + c], 0, 0, 0);
    }
}

// f16-A core: stage A+B full-K, ONE barrier, 8 MFMA steps
__device__ __forceinline__ void core_f16(
    const _Float16* __restrict__ A, const _Float16* __restrict__ Bt,
    int bm, int bn, _Float16* Ash, _Float16* Bsh, f32x4 (&acc)[2][8])
{
    const int tid = threadIdx.x;
    const int wave = tid >> 6, lane = tid & 63;
    const int quad = lane >> 4, l16 = lane & 15;
    stage_B(Bt, bn, Bsh, tid);
    #pragma unroll
    for (int j = 0; j < 16; ++j) {
        const int s = tid + 256 * j;
        const int row = s >> 5, phys = s & 31;
        const int cl = phys ^ (row & 7);
        async16(A + (size_t)(bm + row) * 256 + cl * 8, Ash + s * 8);
    }
    __syncthreads();
    #pragma unroll
    for (int t = 0; t < 8; ++t) {
        f16x8 ah[2];
        #pragma unroll
        for (int r = 0; r < 2; ++r) {
            const int arow = wave * 32 + r * 16 + l16;
            const int pa = (t * 4 + quad) ^ (arow & 7);
            ah[r] = *(const f16x8*)&Ash[arow * 256 + pa * 8];
        }
        mfma_step(Bsh, ah, t, quad, l16, acc);
    }
}

// f32-A core: B full-K f16; A kept f32 in LDS, half-K per phase (64 KB),
// cvt f32->f16 during fragment read. 3 barriers total.
__device__ __forceinline__ void core_f32(
    const float* __restrict__ A, const _Float16* __restrict__ Bt,
    int bm, int bn, float* AshF, _Float16* Bsh, f32x4 (&acc)[2][8])
{
    const int tid = threadIdx.x;
    const int wave = tid >> 6, lane = tid & 63;
    const int quad = lane >> 4, l16 = lane & 15;
    stage_B(Bt, bn, Bsh, tid);
    #pragma unroll
    for (int h = 0; h < 2; ++h) {
        // stage A half-K f32: [128 rows][128 k] f32, 16B slot = 4 f32, 32 slots/row
        #pragma unroll
        for (int j = 0; j < 16; ++j) {
            const int s = tid + 256 * j;
            const int row = s >> 5, phys = s & 31;
            const int cl = phys ^ (row & 7);
            async16(A + (size_t)(bm + row) * 256 + h * 128 + cl * 4, AshF + s * 4);
        }
        __syncthreads();
        #pragma unroll
        for (int tt = 0; tt < 4; ++tt) {
            const int t = h * 4 + tt;
            f16x8 ah[2];
            #pragma unroll
            for (int r = 0; r < 2; ++r) {
                const int arow = wave * 32 + r * 16 + l16;
                const int cl0 = tt * 8 + quad * 2;
                const int p0 = cl0       ^ (arow & 7);
                const int p1 = (cl0 + 1) ^ (arow & 7);
                const f32x4 a0 = *(const f32x4*)&AshF[arow * 128 + p0 * 4];
                const f32x4 a1 = *(const f32x4*)&AshF[arow * 128 + p1 * 4];
                f16x8 hh;
                hh[0] = (_Float16)a0[0]; hh[1] = (_Float16)a0[1];
                hh[2] = (_Float16)a0[2]; hh[3] = (_Float16)a0[3];
                hh[4] = (_Float16)a1[0]; hh[5] = (_Float16)a1[1];
                hh[6] = (_Float16)a1[2]; hh[7] = (_Float16)a1[3];
                ah[r] = hh;
            }
            mfma_step(Bsh, ah, t, quad, l16, acc);
        }
        if (h == 0) __syncthreads();   // all reads of A-half0 done before overwrite
    }
}

// ---- merged GEMM1 (value, head-major f16 out) + GEMM2 (off|attn, routed f32 out)
// GEMM1: 680 blocks (340y x 2x), A=IF f32.  GEMM2: 768 blocks (256y x 3x), A=query f32.
__global__ __launch_bounds__(256) void gemm12_fullk(
    const float* __restrict__ IF, const float* __restrict__ Q,
    const _Float16* __restrict__ Wvt, const _Float16* __restrict__ Wct,
    const float* __restrict__ b_val, const float* __restrict__ b_off,
    const float* __restrict__ b_attn,
    _Float16* __restrict__ value16, float* __restrict__ offbuf, float* __restrict__ attnbuf)
{
    __shared__ __align__(16) float    AshF[128 * 128];   // 64 KB
    __shared__ __align__(16) _Float16 Bsh[128 * 256];    // 64 KB
    f32x4 acc[2][8] = {};
    const int tid = threadIdx.x;
    const int wave = tid >> 6, lane = tid & 63;
    const int quad = lane >> 4, l16 = lane & 15;
    const int bid = blockIdx.x;

    if (bid < 680) {
        const int bm = (bid >> 1) * 128, bn = (bid & 1) * 128;
        core_f32(IF, Wvt, bm, bn, AshF, Bsh, acc);
        gemm_epilogue<2>(acc, bm, bn, wave, quad, l16,
                         b_val, b_val, value16, value16, 256, 256);
    } else {
        const int r = bid - 680;
        const int bm = (r / 3) * 128, bn = (r % 3) * 128;
        core_f32(Q, Wct, bm, bn, AshF, Bsh, acc);
        gemm_epilogue<0>(acc, bm, bn, wave, quad, l16,
                         b_off, b_attn, offbuf, attnbuf, 384, 256);
    }
}

// ---- GEMM3: out = sampled(f16) @ Wot + b_out, f32 flat out
__global__ __launch_bounds__(256) void gemm3_fullk(
    const _Float16* __restrict__ A, const _Float16* __restrict__ Wot,
    const float* __restrict__ b_out, float* __restrict__ out)
{
    __shared__ __align__(16) _Float16 Ash[128 * 256];    // 64 KB
    __shared__ __align__(16) _Float16 Bsh[128 * 256];    // 64 KB
    f32x4 acc[2][8] = {};
    const int tid = threadIdx.x;
    const int wave = tid >> 6, lane = tid & 63;
    const int quad = lane >> 4, l16 = lane & 15;
    const int bm = blockIdx.y * 128, bn = blockIdx.x * 128;
    core_f16(A, Wot, bm, bn, Ash, Bsh, acc);
    gemm_epilogue<0>(acc, bm, bn, wave, quad, l16,
                     b_out, b_out, out, out, 256, 256);
}

// ---------------- sampling v10: 8 queries/block, 16 B/lane gathers ----------------
// Phase 1: 1024 tasks (q,m,pt), 4 iters; fused 16-lane shuffle softmax; writes
//   ivt/wvt with m^(pt&7) XOR column -> <=2-way LDS on both write & read (free).
// Phase 2: thread (q, m, d8-quarter) owns 8 channels -> f16x8 (16 B) gathers:
//   halves gather/address instruction count per query vs v9 (VALUBusy was 56%).
// Reference quirk preserved: sample (l,p) weighted by attn[..., p, l].
__global__ __launch_bounds__(256) void sample_kernel_v10(
    const _Float16* __restrict__ value,  // (MH, NPIX, 32) f16 head-major
    const float* __restrict__ off,       // (N*LQ, 256)
    const float* __restrict__ attn,      // (N*LQ, 128) RAW logits
    _Float16* __restrict__ outv)
{
    __shared__ __align__(16) int4   ivt[128][8];   // 16 KB
    __shared__ __align__(16) float4 wvt[128][8];   // 16 KB

    const int tid = threadIdx.x;
    const int qbase = blockIdx.x * 8;

    #pragma unroll
    for (int j = 0; j < 4; ++j) {
        const int t  = tid + 256 * j;
        const int q  = t >> 7;
        const int m  = (t >> 4) & 7;
        const int pt = t & 15;          // pt = l*4 + p
        const int l  = pt >> 2;
        const int p  = pt & 3;
        const int qi = qbase + q;
        const int lq = qi & (LQ - 1);
        const int n  = qi >> 14;

        const int Hl = 128 >> l;
        const int STARTS[4] = {0, 16384, 20480, 21504};

        const float2 oxy = *(const float2*)&off[(size_t)qi * 256 + m * 32 + pt * 2];

        // fused softmax over the 16 logits of this (q,m) group (16-lane bijection)
        const float logit = attn[(size_t)qi * 128 + m * 16 + p * 4 + l];
        float mx = logit;
        #pragma unroll
        for (int d = 1; d < 16; d <<= 1) mx = fmaxf(mx, __shfl_xor(mx, d, 16));
        const float e = __expf(logit - mx);
        float sm = e;
        #pragma unroll
        for (int d = 1; d < 16; d <<= 1) sm += __shfl_xor(sm, d, 16);
        const float w = e / sm;

        const float refx = ((lq & 127) + 0.5f) * (1.0f / 128.0f);
        const float refy = ((lq >> 7)  + 0.5f) * (1.0f / 128.0f);

        const float x = refx * (float)Hl + oxy.x - 0.5f;
        const float y = refy * (float)Hl + oxy.y - 0.5f;
        const float x0f = floorf(x), y0f = floorf(y);
        const int x0 = (int)x0f, y0 = (int)y0f;
        const int x1 = x0 + 1,  y1 = y0 + 1;
        const float fx = x - x0f, fy = y - y0f;
        const float gx = 1.f - fx, gy = 1.f - fy;

        const float vx0 = (x0 >= 0 && x0 < Hl) ? 1.f : 0.f;
        const float vx1 = (x1 >= 0 && x1 < Hl) ? 1.f : 0.f;
        const float vy0 = (y0 >= 0 && y0 < Hl) ? 1.f : 0.f;
        const float vy1 = (y1 >= 0 && y1 < Hl) ? 1.f : 0.f;

        const int x0c = min(max(x0, 0), Hl - 1);
        const int x1c = min(max(x1, 0), Hl - 1);
        const int y0c = min(max(y0, 0), Hl - 1);
        const int y1c = min(max(y1, 0), Hl - 1);

        // head-major BYTE offsets; pixel stride 64 B
        const int baseb = m * (NPIX * 64) + (n * LIN + STARTS[l]) * 64;
        const int i00 = baseb + (y0c * Hl + x0c) * 64;
        const int i01 = baseb + (y0c * Hl + x1c) * 64;
        const int i10 = baseb + (y1c * Hl + x0c) * 64;
        const int i11 = baseb + (y1c * Hl + x1c) * 64;

        float4 wv;
        wv.x = w * gy * gx * vy0 * vx0;
        wv.y = w * gy * fx * vy0 * vx1;
        wv.z = w * fy * gx * vy1 * vx0;
        wv.w = w * fy * fx * vy1 * vx1;

        const int cc = m ^ (pt & 7);          // XOR col: conflict-free both phases
        int4 iv = {i00, i01, i10, i11};
        ivt[q * 16 + pt][cc] = iv;
        wvt[q * 16 + pt][cc] = wv;
    }
    __syncthreads();

    // ---- Phase 2: f16x8 gathers (16 B/lane) + vector weighted accumulate ----
    const int q  = tid >> 5;
    const int m  = (tid >> 2) & 7;
    const int d8 = tid & 3;
    const int qi = qbase + q;
    const unsigned dd = (unsigned)(d8 * 16);   // byte offset of this lane's 8 ch
    const char* vp = (const char*)value;

    f32x4 accL = {0.f, 0.f, 0.f, 0.f};
    f32x4 accH = {0.f, 0.f, 0.f, 0.f};
    #pragma unroll
    for (int pt = 0; pt < 16; ++pt) {
        const int cc = m ^ (pt & 7);
        const int4  iv = ivt[q * 16 + pt][cc];
        const float4 wv = wvt[q * 16 + pt][cc];
        const f16x8 v00 = *(const f16x8*)(vp + ((unsigned)iv.x + dd));
        const f16x8 v01 = *(const f16x8*)(vp + ((unsigned)iv.y + dd));
        const f16x8 v10 = *(const f16x8*)(vp + ((unsigned)iv.z + dd));
        const f16x8 v11 = *(const f16x8*)(vp + ((unsigned)iv.w + dd));
        f32x4 l00 = {(float)v00[0], (float)v00[1], (float)v00[2], (float)v00[3]};
        f32x4 h00 = {(float)v00[4], (float)v00[5], (float)v00[6], (float)v00[7]};
        f32x4 l01 = {(float)v01[0], (float)v01[1], (float)v01[2], (float)v01[3]};
        f32x4 h01 = {(float)v01[4], (float)v01[5], (float)v01[6], (float)v01[7]};
        f32x4 l10 = {(float)v10[0], (float)v10[1], (float)v10[2], (float)v10[3]};
        f32x4 h10 = {(float)v10[4], (float)v10[5], (float)v10[6], (float)v10[7]};
        f32x4 l11 = {(float)v11[0], (float)v11[1], (float)v11[2], (float)v11[3]};
        f32x4 h11 = {(float)v11[4], (float)v11[5], (float)v11[6], (float)v11[7]};
        accL += wv.x * l00 + wv.y * l01 + wv.z * l10 + wv.w * l11;
        accH += wv.x * h00 + wv.y * h01 + wv.z * h10 + wv.w * h11;
    }

    f16x8 o;
    o[0] = (_Float16)accL[0]; o[1] = (_Float16)accL[1];
    o[2] = (_Float16)accL[2]; o[3] = (_Float16)accL[3];
    o[4] = (_Float16)accH[0]; o[5] = (_Float16)accH[1];
    o[6] = (_Float16)accH[2]; o[7] = (_Float16)accH[3];
    *(f16x8*)&outv[(size_t)qi * 256 + m * 32 + d8 * 8] = o;
}

// ---------------- launch ----------------
extern "C" void kernel_launch(void* const* d_in, const int* in_sizes, int n_in,
                              void* d_out, int out_size, void* d_ws, size_t ws_size,
                              hipStream_t stream)
{
    const float* query         = (const float*)d_in[0];
    const float* input_flatten = (const float*)d_in[2];
    const float* W_off  = (const float*)d_in[5];
    const float* b_off  = (const float*)d_in[6];
    const float* W_attn = (const float*)d_in[7];
    const float* b_attn = (const float*)d_in[8];
    const float* W_val  = (const float*)d_in[9];
    const float* b_val  = (const float*)d_in[10];
    const float* W_out  = (const float*)d_in[11];
    const float* b_out  = (const float*)d_in[12];
    float* out = (float*)d_out;

    char* w = (char*)d_ws;
    _Float16* Sf16 = (_Float16*)w;                     // 16.8 MB, sampler->outGEMM
    _Float16* value16 = (_Float16*)(w + 23068672);     // (8, 43520, 32) f16 (22.3 MB)
    float*    attnbuf = (float*)(w + 67633152);        // 32768x128 f32 raw logits
    _Float16* Wvt = (_Float16*)(w + 84410368);         // [256][256] f16
    _Float16* Wot = Wvt + 65536;                       // [256][256] f16
    _Float16* Wct = Wot + 65536;                       // [384][256] f16 (off|attn)
    float* offbuf = out;   // off staged in d_out, consumed before final GEMM

    dim3 blk(256);

    // weight transforms (one merged launch)
    tsplit_all_kernel<<<896, blk, 0, stream>>>(W_val, W_out, W_off, W_attn, Wvt, Wot, Wct);

    // 1+2) merged full-K GEMMs: value (head-major f16) || off|attn (routed f32)
    gemm12_fullk<<<1448, blk, 0, stream>>>(
        input_flatten, query, Wvt, Wct, b_val, b_off, b_attn,
        value16, offbuf, attnbuf);

    // 3) sampling: fused softmax + f16 head-major taps -> f16 sampled
    sample_kernel_v10<<<4096, blk, 0, stream>>>(value16, offbuf, attnbuf, Sf16);

    // 4) out = sampled @ W_out + b_out (full-K f16 GEMM)
    gemm3_fullk<<<dim3(2, 256), blk, 0, stream>>>(Sf16, Wot, b_out, out);
}

// Round 5
// 225.299 us; speedup vs baseline: 1.1468x; 1.0531x over previous
//
#include <hip/hip_runtime.h>
#include <math.h>

// Problem constants (fixed by reference file)
#define NB   2
#define LQ   16384
#define CDIM 256
#define MH   8          // heads
#define DH   32         // head dim
#define LIN  21760      // 128^2+64^2+32^2+16^2
#define NPIX (NB * LIN) // 43520 total pixels across batch

typedef __attribute__((ext_vector_type(8))) _Float16 f16x8;
typedef __attribute__((ext_vector_type(4))) _Float16 f16x4;
typedef __attribute__((ext_vector_type(4))) float    f32x4;

// async 16B global->LDS (wave-uniform LDS base + lane*16 — no padding allowed)
__device__ __forceinline__ void async16(const void* g, void* l) {
    __builtin_amdgcn_global_load_lds(
        (const __attribute__((address_space(1))) void*)g,
        (__attribute__((address_space(3))) void*)l,
        16, 0, 0);
}

// XCD-aware block swizzle (T1): consecutive work-ids land on ONE XCD's L2
// so bn-paired blocks sharing an A row-panel reuse it. Requires nwg % 8 == 0.
__device__ __forceinline__ int xcd_swizzle(int b, int nwg) {
    return (b & 7) * (nwg >> 3) + (b >> 3);
}

// ---------------- merged weight transposes: W[k][n] f32 -> t[n][k] f16 ----------
__global__ __launch_bounds__(256) void tsplit_all_kernel(
    const float* __restrict__ Wv, const float* __restrict__ Wo,
    const float* __restrict__ Wf, const float* __restrict__ Wa,
    _Float16* __restrict__ Wvt, _Float16* __restrict__ Wot, _Float16* __restrict__ Wct)
{
    const int i = blockIdx.x * 256 + threadIdx.x;   // 896*256 exact
    const int r = i >> 8;
    const int kk = i & 255;
    if (r < 256) {
        Wvt[r * 256 + kk] = (_Float16)Wv[kk * 256 + r];
    } else if (r < 512) {
        const int n = r - 256;
        Wot[n * 256 + kk] = (_Float16)Wo[kk * 256 + n];
    } else if (r < 768) {
        const int n = r - 512;
        Wct[n * 256 + kk] = (_Float16)Wf[kk * 256 + n];
    } else {
        const int n = r - 768;
        Wct[(256 + n) * 256 + kk] = (_Float16)Wa[kk * 128 + n];
    }
}

// ================= GEMM v3: 64 KB LDS (2 blocks/CU), two K=128 phases =================
// R4 showed full-K (128 KB LDS, 1 block/CU, 4 waves) is latency-bound: MfmaUtil 7%,
// Occupancy 9% — nothing resident to cover the stage drain. v3 keeps few barriers
// (3/block) but halves LDS: Ash f16 [128][128] 32 KB + Bsh f16 [128][128] 32 KB.
// 2 blocks/CU -> 8 waves/CU: one block's MFMAs cover the other's drain (m114).
// f32-A path: A register-staged (loads -> cvt f16 -> swizzled ds_write) = 32 KB;
// B always global_load_lds with both-sides XOR swizzle (rule #21):
//   16B-chunk phys = logical ^ (row & 7)  (16 chunks per 128-f16 row)
//   -> all ds_read_b128 / ds_write_b128 are <=2 lanes/bank (free).
// MFMA operand-swapped (bh, ah): thread holds 4 consecutive C-cols -> wide stores.

// stage one K=128 half of a f16 [128 rows][256] matrix via global_load_lds
__device__ __forceinline__ void stage_f16_half(
    const _Float16* __restrict__ Src, int brow0, int ph, _Float16* Dsh, int tid)
{
    #pragma unroll
    for (int j = 0; j < 8; ++j) {
        const int s = tid + 256 * j;          // LDS 16B slot; 16 slots/row
        const int row = s >> 4, ch = s & 15;
        const int cl = ch ^ (row & 7);        // inverse-swizzled source chunk
        async16(Src + (size_t)(brow0 + row) * 256 + ph * 128 + cl * 8, Dsh + s * 8);
    }
}

// 4 k32-steps of MFMA on the current 128-wide K-phase
__device__ __forceinline__ void mfma_phase(
    const _Float16* Ash, const _Float16* Bsh, int wave, int quad, int l16,
    f32x4 (&acc)[2][8])
{
    #pragma unroll
    for (int t = 0; t < 4; ++t) {
        f16x8 ah[2];
        #pragma unroll
        for (int r = 0; r < 2; ++r) {
            const int arow = wave * 32 + r * 16 + l16;
            const int pa = (t * 4 + quad) ^ (arow & 7);
            ah[r] = *(const f16x8*)&Ash[arow * 128 + pa * 8];
        }
        #pragma unroll
        for (int half = 0; half < 2; ++half) {
            f16x8 bh[4];
            #pragma unroll
            for (int c = 0; c < 4; ++c) {
                const int brow = half * 64 + c * 16 + l16;
                const int pb = (t * 4 + quad) ^ (brow & 7);
                bh[c] = *(const f16x8*)&Bsh[brow * 128 + pb * 8];
            }
            #pragma unroll
            for (int r = 0; r < 2; ++r)
                #pragma unroll
                for (int c = 0; c < 4; ++c)
                    acc[r][half * 4 + c] = __builtin_amdgcn_mfma_f32_16x16x32_f16(
                        bh[c], ah[r], acc[r][half * 4 + c], 0, 0, 0);
        }
    }
}

// f32-A core: per phase — A reg-loads issued, B DMA issued (overlaps A cvt/write),
// A cvt+swizzled ds_write, barrier, 4 MFMA steps. 3 barriers total.
__device__ __forceinline__ void core_f32_128(
    const float* __restrict__ A, const _Float16* __restrict__ Bt,
    int bm, int bn, _Float16* Ash, _Float16* Bsh, f32x4 (&acc)[2][8])
{
    const int tid = threadIdx.x;
    const int wave = tid >> 6, lane = tid & 63;
    const int quad = lane >> 4, l16 = lane & 15;
    #pragma unroll
    for (int ph = 0; ph < 2; ++ph) {
        if (ph) __syncthreads();               // prior-phase reads done before overwrite
        float4 r0[8], r1[8];
        #pragma unroll
        for (int i = 0; i < 8; ++i) {          // A: 16 dwordx4 loads, issued first
            const int v = tid + 256 * i;
            const int row = v >> 4, ch = v & 15;
            const float* src = A + (size_t)(bm + row) * 256 + ph * 128 + ch * 8;
            r0[i] = *(const float4*)src;
            r1[i] = *(const float4*)(src + 4);
        }
        stage_f16_half(Bt, bn, ph, Bsh, tid);  // B DMA in flight during A cvt/writes
        #pragma unroll
        for (int i = 0; i < 8; ++i) {
            const int v = tid + 256 * i;
            const int row = v >> 4, ch = v & 15;
            f16x8 h;
            h[0] = (_Float16)r0[i].x; h[1] = (_Float16)r0[i].y;
            h[2] = (_Float16)r0[i].z; h[3] = (_Float16)r0[i].w;
            h[4] = (_Float16)r1[i].x; h[5] = (_Float16)r1[i].y;
            h[6] = (_Float16)r1[i].z; h[7] = (_Float16)r1[i].w;
            *(f16x8*)&Ash[row * 128 + ((ch ^ (row & 7)) * 8)] = h;
        }
        __syncthreads();                       // drains B DMA + A LDS writes
        mfma_phase(Ash, Bsh, wave, quad, l16, acc);
    }
}

// f16-A core: both operands via global_load_lds. 3 barriers total.
__device__ __forceinline__ void core_f16_128(
    const _Float16* __restrict__ A, const _Float16* __restrict__ Bt,
    int bm, int bn, _Float16* Ash, _Float16* Bsh, f32x4 (&acc)[2][8])
{
    const int tid = threadIdx.x;
    const int wave = tid >> 6, lane = tid & 63;
    const int quad = lane >> 4, l16 = lane & 15;
    #pragma unroll
    for (int ph = 0; ph < 2; ++ph) {
        if (ph) __syncthreads();
        stage_f16_half(A, bm, ph, Ash, tid);
        stage_f16_half(Bt, bn, ph, Bsh, tid);
        __syncthreads();
        mfma_phase(Ash, Bsh, wave, quad, l16, acc);
    }
}

// epilogue: C-row = bm+wave*32+r*16+l16, C-col = bn+cidx*16+quad*4+i
// OUT_MODE: 0 = f32 flat, 2 = f16 head-major (m, pixel, 32ch).
template <int OUT_MODE>
__device__ __forceinline__ void gemm_epilogue(
    f32x4 (&acc)[2][8], int bm, int bn, int wave, int quad, int l16,
    const float* bias0, const float* bias1, void* C0, void* C1, int N, int N0)
{
    void* Cb; const float* bb; int ldc, coff;
    if (bn < N0) { Cb = C0; bb = bias0; ldc = N0;     coff = 0;  }
    else         { Cb = C1; bb = bias1; ldc = N - N0; coff = N0; }
    #pragma unroll
    for (int cidx = 0; cidx < 8; ++cidx) {
        const int col = bn + cidx * 16 + quad * 4 - coff;   // 4 consecutive cols
        const float4 bia = *(const float4*)&bb[col];
        #pragma unroll
        for (int r = 0; r < 2; ++r) {
            const int rr = bm + wave * 32 + r * 16 + l16;
            float4 v;
            v.x = acc[r][cidx][0] + bia.x;
            v.y = acc[r][cidx][1] + bia.y;
            v.z = acc[r][cidx][2] + bia.z;
            v.w = acc[r][cidx][3] + bia.w;
            if (OUT_MODE == 0) {
                *(float4*)&((float*)Cb)[(size_t)rr * ldc + col] = v;
            } else {
                f16x4 h;
                h[0] = (_Float16)v.x; h[1] = (_Float16)v.y;
                h[2] = (_Float16)v.z; h[3] = (_Float16)v.w;
                *(f16x4*)&((_Float16*)Cb)[((size_t)(col >> 5) * NPIX + rr) * 32 + (col & 31)] = h;
            }
        }
    }
}

// ---- merged GEMM1 (value, head-major f16 out) + GEMM2 (off|attn, routed f32 out)
// GEMM1: 680 work-ids (340y x 2x), A=IF f32.  GEMM2: 768 (256y x 3x), A=query f32.
__global__ __launch_bounds__(256) void gemm12_v3(
    const float* __restrict__ IF, const float* __restrict__ Q,
    const _Float16* __restrict__ Wvt, const _Float16* __restrict__ Wct,
    const float* __restrict__ b_val, const float* __restrict__ b_off,
    const float* __restrict__ b_attn,
    _Float16* __restrict__ value16, float* __restrict__ offbuf, float* __restrict__ attnbuf)
{
    __shared__ __align__(16) _Float16 Ash[128 * 128];    // 32 KB
    __shared__ __align__(16) _Float16 Bsh[128 * 128];    // 32 KB
    f32x4 acc[2][8] = {};
    const int tid = threadIdx.x;
    const int wave = tid >> 6, lane = tid & 63;
    const int quad = lane >> 4, l16 = lane & 15;
    const int wid = xcd_swizzle(blockIdx.x, 1448);       // 1448 % 8 == 0

    if (wid < 680) {
        const int bm = (wid >> 1) * 128, bn = (wid & 1) * 128;
        core_f32_128(IF, Wvt, bm, bn, Ash, Bsh, acc);
        gemm_epilogue<2>(acc, bm, bn, wave, quad, l16,
                         b_val, b_val, value16, value16, 256, 256);
    } else {
        const int r = wid - 680;
        const int bm = (r / 3) * 128, bn = (r % 3) * 128;
        core_f32_128(Q, Wct, bm, bn, Ash, Bsh, acc);
        gemm_epilogue<0>(acc, bm, bn, wave, quad, l16,
                         b_off, b_attn, offbuf, attnbuf, 384, 256);
    }
}

// ---- GEMM3: out = sampled(f16) @ Wot + b_out, f32 flat out. 512 work-ids.
__global__ __launch_bounds__(256) void gemm3_v3(
    const _Float16* __restrict__ A, const _Float16* __restrict__ Wot,
    const float* __restrict__ b_out, float* __restrict__ out)
{
    __shared__ __align__(16) _Float16 Ash[128 * 128];    // 32 KB
    __shared__ __align__(16) _Float16 Bsh[128 * 128];    // 32 KB
    f32x4 acc[2][8] = {};
    const int tid = threadIdx.x;
    const int wave = tid >> 6, lane = tid & 63;
    const int quad = lane >> 4, l16 = lane & 15;
    const int wid = xcd_swizzle(blockIdx.x, 512);        // 512 % 8 == 0
    const int bm = (wid >> 1) * 128, bn = (wid & 1) * 128;
    core_f16_128(A, Wot, bm, bn, Ash, Bsh, acc);
    gemm_epilogue<0>(acc, bm, bn, wave, quad, l16,
                     b_out, b_out, out, out, 256, 256);
}

// ---------------- sampling v10: 8 queries/block, 16 B/lane gathers ----------------
// (unchanged from R4 — verified 60.9 µs, near the L2-line ceiling)
__global__ __launch_bounds__(256) void sample_kernel_v10(
    const _Float16* __restrict__ value,  // (MH, NPIX, 32) f16 head-major
    const float* __restrict__ off,       // (N*LQ, 256)
    const float* __restrict__ attn,      // (N*LQ, 128) RAW logits
    _Float16* __restrict__ outv)
{
    __shared__ __align__(16) int4   ivt[128][8];   // 16 KB
    __shared__ __align__(16) float4 wvt[128][8];   // 16 KB

    const int tid = threadIdx.x;
    const int qbase = blockIdx.x * 8;

    #pragma unroll
    for (int j = 0; j < 4; ++j) {
        const int t  = tid + 256 * j;
        const int q  = t >> 7;
        const int m  = (t >> 4) & 7;
        const int pt = t & 15;          // pt = l*4 + p
        const int l  = pt >> 2;
        const int p  = pt & 3;
        const int qi = qbase + q;
        const int lq = qi & (LQ - 1);
        const int n  = qi >> 14;

        const int Hl = 128 >> l;
        const int STARTS[4] = {0, 16384, 20480, 21504};

        const float2 oxy = *(const float2*)&off[(size_t)qi * 256 + m * 32 + pt * 2];

        // fused softmax over the 16 logits of this (q,m) group (16-lane bijection)
        const float logit = attn[(size_t)qi * 128 + m * 16 + p * 4 + l];
        float mx = logit;
        #pragma unroll
        for (int d = 1; d < 16; d <<= 1) mx = fmaxf(mx, __shfl_xor(mx, d, 16));
        const float e = __expf(logit - mx);
        float sm = e;
        #pragma unroll
        for (int d = 1; d < 16; d <<= 1) sm += __shfl_xor(sm, d, 16);
        const float w = e / sm;

        const float refx = ((lq & 127) + 0.5f) * (1.0f / 128.0f);
        const float refy = ((lq >> 7)  + 0.5f) * (1.0f / 128.0f);

        const float x = refx * (float)Hl + oxy.x - 0.5f;
        const float y = refy * (float)Hl + oxy.y - 0.5f;
        const float x0f = floorf(x), y0f = floorf(y);
        const int x0 = (int)x0f, y0 = (int)y0f;
        const int x1 = x0 + 1,  y1 = y0 + 1;
        const float fx = x - x0f, fy = y - y0f;
        const float gx = 1.f - fx, gy = 1.f - fy;

        const float vx0 = (x0 >= 0 && x0 < Hl) ? 1.f : 0.f;
        const float vx1 = (x1 >= 0 && x1 < Hl) ? 1.f : 0.f;
        const float vy0 = (y0 >= 0 && y0 < Hl) ? 1.f : 0.f;
        const float vy1 = (y1 >= 0 && y1 < Hl) ? 1.f : 0.f;

        const int x0c = min(max(x0, 0), Hl - 1);
        const int x1c = min(max(x1, 0), Hl - 1);
        const int y0c = min(max(y0, 0), Hl - 1);
        const int y1c = min(max(y1, 0), Hl - 1);

        // head-major BYTE offsets; pixel stride 64 B
        const int baseb = m * (NPIX * 64) + (n * LIN + STARTS[l]) * 64;
        const int i00 = baseb + (y0c * Hl + x0c) * 64;
        const int i01 = baseb + (y0c * Hl + x1c) * 64;
        const int i10 = baseb + (y1c * Hl + x0c) * 64;
        const int i11 = baseb + (y1c * Hl + x1c) * 64;

        float4 wv;
        wv.x = w * gy * gx * vy0 * vx0;
        wv.y = w * gy * fx * vy0 * vx1;
        wv.z = w * fy * gx * vy1 * vx0;
        wv.w = w * fy * fx * vy1 * vx1;

        const int cc = m ^ (pt & 7);          // XOR col: conflict-free both phases
        int4 iv = {i00, i01, i10, i11};
        ivt[q * 16 + pt][cc] = iv;
        wvt[q * 16 + pt][cc] = wv;
    }
    __syncthreads();

    // ---- Phase 2: f16x8 gathers (16 B/lane) + vector weighted accumulate ----
    const int q  = tid >> 5;
    const int m  = (tid >> 2) & 7;
    const int d8 = tid & 3;
    const int qi = qbase + q;
    const unsigned dd = (unsigned)(d8 * 16);   // byte offset of this lane's 8 ch
    const char* vp = (const char*)value;

    f32x4 accL = {0.f, 0.f, 0.f, 0.f};
    f32x4 accH = {0.f, 0.f, 0.f, 0.f};
    #pragma unroll
    for (int pt = 0; pt < 16; ++pt) {
        const int cc = m ^ (pt & 7);
        const int4  iv = ivt[q * 16 + pt][cc];
        const float4 wv = wvt[q * 16 + pt][cc];
        const f16x8 v00 = *(const f16x8*)(vp + ((unsigned)iv.x + dd));
        const f16x8 v01 = *(const f16x8*)(vp + ((unsigned)iv.y + dd));
        const f16x8 v10 = *(const f16x8*)(vp + ((unsigned)iv.z + dd));
        const f16x8 v11 = *(const f16x8*)(vp + ((unsigned)iv.w + dd));
        f32x4 l00 = {(float)v00[0], (float)v00[1], (float)v00[2], (float)v00[3]};
        f32x4 h00 = {(float)v00[4], (float)v00[5], (float)v00[6], (float)v00[7]};
        f32x4 l01 = {(float)v01[0], (float)v01[1], (float)v01[2], (float)v01[3]};
        f32x4 h01 = {(float)v01[4], (float)v01[5], (float)v01[6], (float)v01[7]};
        f32x4 l10 = {(float)v10[0], (float)v10[1], (float)v10[2], (float)v10[3]};
        f32x4 h10 = {(float)v10[4], (float)v10[5], (float)v10[6], (float)v10[7]};
        f32x4 l11 = {(float)v11[0], (float)v11[1], (float)v11[2], (float)v11[3]};
        f32x4 h11 = {(float)v11[4], (float)v11[5], (float)v11[6], (float)v11[7]};
        accL += wv.x * l00 + wv.y * l01 + wv.z * l10 + wv.w * l11;
        accH += wv.x * h00 + wv.y * h01 + wv.z * h10 + wv.w * h11;
    }

    f16x8 o;
    o[0] = (_Float16)accL[0]; o[1] = (_Float16)accL[1];
    o[2] = (_Float16)accL[2]; o[3] = (_Float16)accL[3];
    o[4] = (_Float16)accH[0]; o[5] = (_Float16)accH[1];
    o[6] = (_Float16)accH[2]; o[7] = (_Float16)accH[3];
    *(f16x8*)&outv[(size_t)qi * 256 + m * 32 + d8 * 8] = o;
}

// ---------------- launch ----------------
extern "C" void kernel_launch(void* const* d_in, const int* in_sizes, int n_in,
                              void* d_out, int out_size, void* d_ws, size_t ws_size,
                              hipStream_t stream)
{
    const float* query         = (const float*)d_in[0];
    const float* input_flatten = (const float*)d_in[2];
    const float* W_off  = (const float*)d_in[5];
    const float* b_off  = (const float*)d_in[6];
    const float* W_attn = (const float*)d_in[7];
    const float* b_attn = (const float*)d_in[8];
    const float* W_val  = (const float*)d_in[9];
    const float* b_val  = (const float*)d_in[10];
    const float* W_out  = (const float*)d_in[11];
    const float* b_out  = (const float*)d_in[12];
    float* out = (float*)d_out;

    char* w = (char*)d_ws;
    _Float16* Sf16 = (_Float16*)w;                     // 16.8 MB, sampler->outGEMM
    _Float16* value16 = (_Float16*)(w + 23068672);     // (8, 43520, 32) f16 (22.3 MB)
    float*    attnbuf = (float*)(w + 67633152);        // 32768x128 f32 raw logits
    _Float16* Wvt = (_Float16*)(w + 84410368);         // [256][256] f16
    _Float16* Wot = Wvt + 65536;                       // [256][256] f16
    _Float16* Wct = Wot + 65536;                       // [384][256] f16 (off|attn)
    float* offbuf = out;   // off staged in d_out, consumed before final GEMM

    dim3 blk(256);

    // weight transforms (one merged launch)
    tsplit_all_kernel<<<896, blk, 0, stream>>>(W_val, W_out, W_off, W_attn, Wvt, Wot, Wct);

    // 1+2) merged GEMMs v3 (2 blocks/CU): value (head-major f16) || off|attn (routed)
    gemm12_v3<<<1448, blk, 0, stream>>>(
        input_flatten, query, Wvt, Wct, b_val, b_off, b_attn,
        value16, offbuf, attnbuf);

    // 3) sampling: fused softmax + f16 head-major taps -> f16 sampled
    sample_kernel_v10<<<4096, blk, 0, stream>>>(value16, offbuf, attnbuf, Sf16);

    // 4) out = sampled @ W_out + b_out (GEMM v3)
    gemm3_v3<<<512, blk, 0, stream>>>(Sf16, Wot, b_out, out);
}